// Round 5
// baseline (717.255 us; speedup 1.0000x reference)
//
#include <hip/hip_runtime.h>

#define NNODES 12288
#define ETOT   73728
#define NGR    1024
#define LOG2E  1.442695041f
#define LN2    0.6931471806f

typedef __attribute__((ext_vector_type(8))) short short8;
typedef __attribute__((ext_vector_type(4))) float f32x4;

__device__ __forceinline__ unsigned short f2b(float f) {
  unsigned x = __float_as_uint(f);
  return (unsigned short)((x + 0x7FFFu + ((x >> 16) & 1u)) >> 16);
}
__device__ __forceinline__ float b2f(unsigned short u) {
  return __uint_as_float(((unsigned)u) << 16);
}
__device__ __forceinline__ void load_lds16(const void* g, void* l) {
  __builtin_amdgcn_global_load_lds(
      (const __attribute__((address_space(1))) unsigned int*)g,
      (__attribute__((address_space(3))) unsigned int*)l, 16, 0, 0);
}
__device__ __forceinline__ unsigned fenc(float f) {
  unsigned u = __float_as_uint(f);
  return (u & 0x80000000u) ? ~u : (u | 0x80000000u);
}
__device__ __forceinline__ float fdec(unsigned e) {
  unsigned u = (e & 0x80000000u) ? (e & 0x7FFFFFFFu) : ~e;
  return __uint_as_float(u);
}

// ---------------------------------------------------------------------------
// Pack (unchanged): transpose-convert all weights to bf16 [N][K].
// ---------------------------------------------------------------------------
__global__ void pack_kernel(
    const float* __restrict__ gat_Wl, const float* __restrict__ gat_Wr,
    const float* __restrict__ cg_Wf, const float* __restrict__ cg_Ws,
    const float* __restrict__ node_W, const float* __restrict__ enc_W,
    const float* __restrict__ fin_W1,
    const float* __restrict__ gat_bl, const float* __restrict__ gat_br,
    const float* __restrict__ cg_bf, const float* __restrict__ cg_bs,
    const float* __restrict__ x_my, const float* __restrict__ x_opp,
    unsigned short* __restrict__ wt_my, unsigned short* __restrict__ wt_opp,
    unsigned short* __restrict__ node_wt, unsigned short* __restrict__ enc_wt,
    unsigned short* __restrict__ fin_w1t,
    float* __restrict__ bias_my, float* __restrict__ bias_opp,
    unsigned short* __restrict__ xb)
{
  int idx = blockIdx.x * 256 + threadIdx.x;
  if (idx < 2 * 2359296) {
    int which = idx >= 2359296;
    int t = which ? idx - 2359296 : idx;
    int l = t / 786432;
    int r = t - l * 786432;
    int n = r >> 8, k = r & 255;
    float v;
    if (!which) {
      if (n < 1024)      v = gat_Wl[((l*2+0)*256 + k)*1024 + n];
      else if (n < 2048) v = gat_Wr[((l*2+1)*256 + k)*1024 + (n-1024)];
      else if (n < 2304) v = cg_Wf[((l*2+0)*512 + 256 + k)*256 + (n-2048)];
      else if (n < 2560) v = cg_Ws[((l*2+0)*512 + 256 + k)*256 + (n-2304)];
      else if (n < 2816) v = cg_Wf[((l*2+1)*512 + k)*256 + (n-2560)];
      else               v = cg_Ws[((l*2+1)*512 + k)*256 + (n-2816)];
      wt_my[t] = f2b(v);
    } else {
      if (n < 1024)      v = gat_Wr[((l*2+0)*256 + k)*1024 + n];
      else if (n < 2048) v = gat_Wl[((l*2+1)*256 + k)*1024 + (n-1024)];
      else if (n < 2304) v = cg_Wf[((l*2+0)*512 + k)*256 + (n-2048)];
      else if (n < 2560) v = cg_Ws[((l*2+0)*512 + k)*256 + (n-2304)];
      else if (n < 2816) v = cg_Wf[((l*2+1)*512 + 256 + k)*256 + (n-2560)];
      else               v = cg_Ws[((l*2+1)*512 + 256 + k)*256 + (n-2816)];
      wt_opp[t] = f2b(v);
    }
    return;
  }
  idx -= 2 * 2359296;
  if (idx < 196608) {
    int l = idx / 65536, r = idx - l * 65536;
    int n = r >> 8, k = r & 255;
    node_wt[idx] = f2b(node_W[(l*256 + k)*256 + n]);
    return;
  }
  idx -= 196608;
  if (idx < 8192) {
    int n = idx >> 5, k = idx & 31;
    enc_wt[idx] = f2b(enc_W[k*256 + n]);
    return;
  }
  idx -= 8192;
  if (idx < 32768) {
    int n = idx >> 8, k = idx & 255;
    fin_w1t[idx] = f2b(fin_W1[k*128 + n]);
    return;
  }
  idx -= 32768;
  if (idx < 9216) {
    int l = idx / 3072, n = idx - l * 3072;
    float v;
    if (n < 1024)      v = gat_bl[(l*2+0)*1024 + n];
    else if (n < 2048) v = gat_br[(l*2+1)*1024 + (n-1024)];
    else if (n < 2560) v = 0.f;
    else if (n < 2816) v = cg_bf[(l*2+1)*256 + (n-2560)];
    else               v = cg_bs[(l*2+1)*256 + (n-2816)];
    bias_my[idx] = v;
    return;
  }
  idx -= 9216;
  if (idx < 9216) {
    int l = idx / 3072, n = idx - l * 3072;
    float v;
    if (n < 1024)      v = gat_br[(l*2+0)*1024 + n];
    else if (n < 2048) v = gat_bl[(l*2+1)*1024 + (n-1024)];
    else if (n < 2304) v = cg_bf[(l*2+0)*256 + (n-2048)];
    else if (n < 2560) v = cg_bs[(l*2+0)*256 + (n-2304)];
    else               v = 0.f;
    bias_opp[idx] = v;
    return;
  }
  idx -= 9216;
  if (idx < 2 * 393216) {
    xb[idx] = f2b(idx < 393216 ? x_my[idx] : x_opp[idx - 393216]);
  }
}

// ---------------------------------------------------------------------------
// bf16 GEMM v3: 128x128 tile, BK=32, 4 waves, 4-buffer LDS ring staged 2
// tiles ahead via global_load_lds; counted s_waitcnt vmcnt(8/4/0) + RAW
// s_barrier (no vmcnt(0) drain in steady state -> loads fly across barriers).
// Swapped-operand MFMA epilogue: lane owns 4 consecutive C columns.
// Dual-source: blocks with blockIdx.x >= bx_split use the second pointer set.
// ---------------------------------------------------------------------------
__global__ __launch_bounds__(256) void gemm128(
    const unsigned short* __restrict__ A, const unsigned short* __restrict__ A2,
    int lda,
    const unsigned short* __restrict__ Wt, const unsigned short* __restrict__ Wt2,
    const float* __restrict__ bias, const float* __restrict__ bias2,
    unsigned short* __restrict__ C, unsigned short* __restrict__ C2,
    int ldc, int K, int act, int bx_split)
{
  __shared__ __align__(16) unsigned short lA[4][128 * 32];
  __shared__ __align__(16) unsigned short lB[4][128 * 32];
  const int tid = threadIdx.x;
  const int lane = tid & 63;
  const int w = tid >> 6;
  const int wr = w >> 1, wc = w & 1;
  const int tileN = blockIdx.y * 128;
  const int r0 = lane & 15;
  const int kq = lane >> 4;
  const int segr = (kq ^ ((r0 >> 1) & 3)) * 8;

  const unsigned short* Ap;
  const unsigned short* Wp;
  const float* bp;
  unsigned short* Cp;
  int tileM;
  if ((int)blockIdx.x < bx_split) {
    Ap = A;  Wp = Wt;  bp = bias;  Cp = C;  tileM = blockIdx.x * 128;
  } else {
    Ap = A2; Wp = Wt2; bp = bias2; Cp = C2; tileM = (blockIdx.x - bx_split) * 128;
  }

  // per-thread staging addresses (hoisted): 2 A-loads + 2 B-loads per tile
  const int rr0 = tid >> 2,        sg0 = tid & 3;
  const int rr1 = (256 + tid) >> 2, sg1 = tid & 3;
  const int ss0 = (sg0 ^ ((rr0 >> 1) & 3)) * 8;
  const int ss1 = (sg1 ^ ((rr1 >> 1) & 3)) * 8;
  const unsigned short* ga0 = Ap + (size_t)(tileM + rr0) * lda + ss0;
  const unsigned short* ga1 = Ap + (size_t)(tileM + rr1) * lda + ss1;
  const unsigned short* gb0 = Wp + (size_t)(tileN + rr0) * K + ss0;
  const unsigned short* gb1 = Wp + (size_t)(tileN + rr1) * K + ss1;
  const int la0 = tid * 8, la1 = (256 + tid) * 8;

  f32x4 acc[4][4];
#pragma unroll
  for (int m = 0; m < 4; ++m)
#pragma unroll
    for (int n = 0; n < 4; ++n)
      acc[m][n] = (f32x4){0.f, 0.f, 0.f, 0.f};

  const int KT = K >> 5;
#define STAGE(kt_, b_)                                  \
  do {                                                  \
    const int k0_ = (kt_) * 32;                         \
    load_lds16(ga0 + k0_, &lA[b_][la0]);                \
    load_lds16(ga1 + k0_, &lA[b_][la1]);                \
    load_lds16(gb0 + k0_, &lB[b_][la0]);                \
    load_lds16(gb1 + k0_, &lB[b_][la1]);                \
  } while (0)

  STAGE(0, 0);
  if (KT > 1) STAGE(1, 1);

  for (int kt = 0; kt < KT; ++kt) {
    if (kt + 2 < KT) STAGE(kt + 2, (kt + 2) & 3);
    const int newer = (kt + 2 < KT ? 2 : (kt + 1 < KT ? 1 : 0));
    if (newer == 2)      asm volatile("s_waitcnt vmcnt(8)" ::: "memory");
    else if (newer == 1) asm volatile("s_waitcnt vmcnt(4)" ::: "memory");
    else                 asm volatile("s_waitcnt vmcnt(0)" ::: "memory");
    __builtin_amdgcn_s_barrier();

    const unsigned short* bufA = lA[kt & 3];
    const unsigned short* bufB = lB[kt & 3];
    short8 af[4], bfr[4];
#pragma unroll
    for (int m = 0; m < 4; ++m)
      af[m] = *(const short8*)&bufA[(wr * 64 + m * 16 + r0) * 32 + segr];
#pragma unroll
    for (int n = 0; n < 4; ++n)
      bfr[n] = *(const short8*)&bufB[(wc * 64 + n * 16 + r0) * 32 + segr];
#pragma unroll
    for (int m = 0; m < 4; ++m)
#pragma unroll
      for (int n = 0; n < 4; ++n)
        acc[m][n] = __builtin_amdgcn_mfma_f32_16x16x32_bf16(bfr[n], af[m], acc[m][n], 0, 0, 0);
  }
#undef STAGE

  // epilogue: lane holds rows tileM+wr*64+m*16+r0, cols n*16+kq*4..+3
#pragma unroll
  for (int m = 0; m < 4; ++m) {
    const int row = tileM + wr * 64 + m * 16 + r0;
    unsigned short* crow = Cp + (size_t)row * ldc;
#pragma unroll
    for (int n = 0; n < 4; ++n) {
      const int col0 = tileN + wc * 64 + n * 16 + kq * 4;
      const f32x4 bv = *(const f32x4*)&bp[col0];
      float v0 = acc[m][n][0] + bv[0];
      float v1 = acc[m][n][1] + bv[1];
      float v2 = acc[m][n][2] + bv[2];
      float v3 = acc[m][n][3] + bv[3];
      if (act) {
        v0 = v0 > 0.f ? v0 : 128.f * v0;
        v1 = v1 > 0.f ? v1 : 128.f * v1;
        v2 = v2 > 0.f ? v2 : 128.f * v2;
        v3 = v3 > 0.f ? v3 : 128.f * v3;
      }
      uint2 pk;
      pk.x = (unsigned)f2b(v0) | ((unsigned)f2b(v1) << 16);
      pk.y = (unsigned)f2b(v2) | ((unsigned)f2b(v3) << 16);
      *(uint2*)(crow + col0) = pk;
    }
  }
}

// ---------------------------------------------------------------------------
// GATv2 edge stage v3 (unchanged): edge-parallel softmax, LDS atomics.
// ---------------------------------------------------------------------------
#define SX 260
__global__ __launch_bounds__(256) void gat_edge(
    const unsigned short* __restrict__ projS,
    const unsigned short* __restrict__ projD,
    const int* __restrict__ edges,
    const float* __restrict__ att,
    const float* __restrict__ gbias,
    float* __restrict__ outp)
{
  __shared__ __align__(16) unsigned short xl[48 * SX];
  __shared__ float attS[4 * SX];
  __shared__ float alphaS[288];
  __shared__ float wS[288];
  __shared__ unsigned mU[48];
  __shared__ float denS[48];
  __shared__ __align__(16) float A2f[12 * 48];
  __shared__ unsigned char se8[72], de8[72];
  const int g = blockIdx.x, tid = threadIdx.x;
  const int base = g * 12;

  if (tid < 72) {
    se8[tid] = (unsigned char)(edges[g * 72 + tid] - base);
    de8[tid] = (unsigned char)(edges[ETOT + g * 72 + tid] - base);
  }
  if (tid < 48) { mU[tid] = 0u; denS[tid] = 0.f; }
  for (int i = tid; i < 576; i += 256) A2f[i] = 0.f;
  for (int i = tid; i < 1024; i += 256)
    attS[(i >> 8) * SX + (i & 255)] = att[i];
  for (int i = tid; i < 3072; i += 256) {
    int s = i >> 8, c4 = (i & 255) * 4;
    int h = c4 >> 8, cc = c4 & 255;
    *(ushort4*)&xl[(h * 12 + s) * SX + cc] =
        *(const ushort4*)(projS + (size_t)(base + s) * 3072 + c4);
  }
  __syncthreads();

  for (int t = tid; t < 288; t += 256) {
    const int e = t >> 2, h = t & 3;
    const unsigned short* pl = &xl[(h * 12 + se8[e]) * SX];
    const unsigned short* pr = projD + (size_t)(base + de8[e]) * 3072 + h * 256;
    const f32x4* pa = (const f32x4*)&attS[h * SX];
    float sum = 0.f;
    for (int q = 0; q < 64; ++q) {
      ushort4 a4 = *(const ushort4*)(pl + q * 4);
      ushort4 b4 = *(const ushort4*)(pr + q * 4);
      f32x4 av = pa[q];
      float v0 = b2f(a4.x) + b2f(b4.x); v0 = fmaxf(v0, 0.2f * v0);
      float v1 = b2f(a4.y) + b2f(b4.y); v1 = fmaxf(v1, 0.2f * v1);
      float v2 = b2f(a4.z) + b2f(b4.z); v2 = fmaxf(v2, 0.2f * v2);
      float v3 = b2f(a4.w) + b2f(b4.w); v3 = fmaxf(v3, 0.2f * v3);
      sum = fmaf(v0, av.x, sum); sum = fmaf(v1, av.y, sum);
      sum = fmaf(v2, av.z, sum); sum = fmaf(v3, av.w, sum);
    }
    sum *= LOG2E;
    alphaS[t] = sum;
    atomicMax(&mU[de8[e] * 4 + h], fenc(sum));
  }
  __syncthreads();

  for (int t = tid; t < 288; t += 256) {
    const int e = t >> 2, h = t & 3;
    const float m = fdec(mU[de8[e] * 4 + h]);
    const float wv = __builtin_amdgcn_exp2f(alphaS[t] - m);
    wS[t] = wv;
    atomicAdd(&denS[de8[e] * 4 + h], wv);
  }
  __syncthreads();

  for (int t = tid; t < 288; t += 256) {
    const int e = t >> 2, h = t & 3;
    const float inv = 0.25f * __builtin_amdgcn_rcpf(denS[de8[e] * 4 + h] + 1e-16f);
    atomicAdd(&A2f[de8[e] * 48 + h * 12 + se8[e]], wS[t] * inv);
  }
  __syncthreads();

  {
    const int c = tid;
    float xlv[48];
#pragma unroll
    for (int j = 0; j < 48; ++j) xlv[j] = b2f(xl[j * SX + c]);
    const float gb = gbias[c];
#pragma unroll
    for (int d = 0; d < 12; ++d) {
      const f32x4* arow = (const f32x4*)&A2f[d * 48];
      float s = 0.f;
#pragma unroll
      for (int jj = 0; jj < 12; ++jj) {
        f32x4 a4 = arow[jj];
        s = fmaf(a4.x, xlv[jj * 4 + 0], s);
        s = fmaf(a4.y, xlv[jj * 4 + 1], s);
        s = fmaf(a4.z, xlv[jj * 4 + 2], s);
        s = fmaf(a4.w, xlv[jj * 4 + 3], s);
      }
      outp[(size_t)(base + d) * 256 + c] = s + gb;
    }
  }
}

// ---------------------------------------------------------------------------
// CGConv edge stage (unchanged).
// ---------------------------------------------------------------------------
__global__ __launch_bounds__(256) void cg_edge(
    const unsigned short* __restrict__ pdF, const unsigned short* __restrict__ pdS,
    const unsigned short* __restrict__ psF, const unsigned short* __restrict__ psS,
    const unsigned short* __restrict__ hres,
    const float* __restrict__ gatp,
    const int* __restrict__ edges,
    unsigned short* __restrict__ outp)
{
  __shared__ __align__(8) unsigned short df[3072], dsb[3072];
  __shared__ __align__(8) unsigned short sfb[3072], ssb[3072];
  __shared__ unsigned char srcl[12 * 80];
  __shared__ int cnt[12];
  __shared__ int se_[72], de_[72];
  const int g = blockIdx.x, tid = threadIdx.x;
  const int base = g * 12;
  if (tid < 72) {
    se_[tid] = edges[g * 72 + tid] - base;
    de_[tid] = edges[ETOT + g * 72 + tid] - base;
  }
  for (int i = tid; i < 768; i += 256) {
    int s = i >> 6, c4 = (i & 63) * 4;
    size_t gb = (size_t)(base + s) * 3072 + c4;
    *(ushort4*)&df[s * 256 + c4]  = *(const ushort4*)(pdF + gb);
    *(ushort4*)&dsb[s * 256 + c4] = *(const ushort4*)(pdS + gb);
    *(ushort4*)&sfb[s * 256 + c4] = *(const ushort4*)(psF + gb);
    *(ushort4*)&ssb[s * 256 + c4] = *(const ushort4*)(psS + gb);
  }
  __syncthreads();
  if (tid < 12) {
    int n = 0;
    for (int e = 0; e < 72; ++e)
      if (de_[e] == tid) srcl[tid * 80 + (n++)] = (unsigned char)se_[e];
    cnt[tid] = n;
  }
  __syncthreads();
  const int c = tid;
  for (int d = 0; d < 12; ++d) {
    const float fd = b2f(df[d * 256 + c]);
    const float sd = b2f(dsb[d * 256 + c]);
    const int n = cnt[d];
    float acc = 0.f;
    for (int j = 0; j < n; ++j) {
      const int s = srcl[d * 80 + j];
      const float zf = fd + b2f(sfb[s * 256 + c]);
      const float zs = sd + b2f(ssb[s * 256 + c]);
      const float gate = __builtin_amdgcn_rcpf(1.f + __builtin_amdgcn_exp2f(-LOG2E * zf));
      const float e2 = __builtin_amdgcn_exp2f(-LOG2E * fabsf(zs));
      const float sp = fmaxf(zs, 0.f) + LN2 * __builtin_amdgcn_logf(1.f + e2);
      acc = fmaf(gate, sp, acc);
    }
    const size_t o = (size_t)(base + d) * 256 + c;
    outp[o] = f2b(b2f(hres[o]) + gatp[o] + acc);
  }
}

// ---------------------------------------------------------------------------
// logits: one wave per node, dot(f[128], W2) + b2
// ---------------------------------------------------------------------------
__global__ __launch_bounds__(256) void logits_kernel(
    const unsigned short* __restrict__ f, const float* __restrict__ W2,
    const float* __restrict__ b2, float* __restrict__ out)
{
  const int node = blockIdx.x * 4 + (threadIdx.x >> 6);
  const int lane = threadIdx.x & 63;
  const size_t o = (size_t)node * 128 + lane * 2;
  float s = b2f(f[o]) * W2[lane * 2] + b2f(f[o + 1]) * W2[lane * 2 + 1];
  for (int d = 32; d > 0; d >>= 1) s += __shfl_down(s, d, 64);
  if (lane == 0) out[node] = s + b2[0];
}

// ---------------------------------------------------------------------------
extern "C" void kernel_launch(void* const* d_in, const int* in_sizes, int n_in,
                              void* d_out, int out_size, void* d_ws, size_t ws_size,
                              hipStream_t stream) {
  const float* x_my    = (const float*)d_in[0];
  const float* x_opp   = (const float*)d_in[1];
  const int*   e_beats = (const int*)d_in[2];
  const int*   e_loses = (const int*)d_in[3];
  const int*   e_rb    = (const int*)d_in[4];
  const int*   e_rl    = (const int*)d_in[5];
  const float* enc_W   = (const float*)d_in[7];
  const float* enc_b   = (const float*)d_in[8];
  const float* gat_Wl  = (const float*)d_in[9];
  const float* gat_bl  = (const float*)d_in[10];
  const float* gat_Wr  = (const float*)d_in[11];
  const float* gat_br  = (const float*)d_in[12];
  const float* gat_att = (const float*)d_in[13];
  const float* gat_bsp = (const float*)d_in[14];
  const float* cg_Wf   = (const float*)d_in[15];
  const float* cg_bf   = (const float*)d_in[16];
  const float* cg_Ws   = (const float*)d_in[17];
  const float* cg_bs   = (const float*)d_in[18];
  const float* node_W  = (const float*)d_in[19];
  const float* node_b  = (const float*)d_in[20];
  const float* fin_W1  = (const float*)d_in[21];
  const float* fin_b1  = (const float*)d_in[22];
  const float* fin_W2  = (const float*)d_in[23];
  const float* fin_b2  = (const float*)d_in[24];

  char* wsp = (char*)d_ws;
  size_t off = 0;
  auto alloc = [&](size_t b) { char* p = wsp + off; off += (b + 255) & ~(size_t)255; return p; };
  unsigned short* wt_my   = (unsigned short*)alloc((size_t)2359296 * 2);
  unsigned short* wt_opp  = (unsigned short*)alloc((size_t)2359296 * 2);
  unsigned short* node_wt = (unsigned short*)alloc((size_t)196608 * 2);
  unsigned short* enc_wt  = (unsigned short*)alloc((size_t)8192 * 2);
  unsigned short* fin_w1t = (unsigned short*)alloc((size_t)32768 * 2);
  float*          bias_my = (float*)alloc((size_t)9216 * 4);
  float*          bias_op = (float*)alloc((size_t)9216 * 4);
  unsigned short* xb      = (unsigned short*)alloc((size_t)786432 * 2);
  unsigned short* Hb      = (unsigned short*)alloc((size_t)2 * NNODES * 256 * 2);
  unsigned short* proj_my = (unsigned short*)alloc((size_t)NNODES * 3072 * 2);
  unsigned short* proj_op = (unsigned short*)alloc((size_t)NNODES * 3072 * 2);
  float*          gat_my  = (float*)alloc((size_t)NNODES * 256 * 4);
  float*          gat_op  = (float*)alloc((size_t)NNODES * 256 * 4);
  unsigned short* node_in = (unsigned short*)alloc((size_t)2 * NNODES * 256 * 2);
  unsigned short* fbuf    = (unsigned short*)alloc((size_t)NNODES * 128 * 2);

  const int PACK_TOTAL = 2 * 2359296 + 196608 + 8192 + 32768 + 2 * 9216 + 2 * 393216;
  pack_kernel<<<(PACK_TOTAL + 255) / 256, 256, 0, stream>>>(
      gat_Wl, gat_Wr, cg_Wf, cg_Ws, node_W, enc_W, fin_W1,
      gat_bl, gat_br, cg_bf, cg_bs, x_my, x_opp,
      wt_my, wt_opp, node_wt, enc_wt, fin_w1t, bias_my, bias_op, xb);

  unsigned short* Hmy   = Hb;
  unsigned short* Hopp  = Hb + (size_t)NNODES * 256;
  unsigned short* ni_my = node_in;
  unsigned short* ni_op = node_in + (size_t)NNODES * 256;

  // encoder: h = x @ enc_W + enc_b  (M = 2N, K = 32)
  gemm128<<<dim3(192, 2), 256, 0, stream>>>(
      xb, xb, 32, enc_wt, enc_wt, enc_b, enc_b, Hb, Hb, 256, 32, 0, 192);

  for (int l = 0; l < 3; ++l) {
    // both proj GEMMs in one dispatch (x-blocks 0..95 = my, 96..191 = opp)
    gemm128<<<dim3(192, 24), 256, 0, stream>>>(
        Hmy, Hopp, 256,
        wt_my + (size_t)l * 786432, wt_opp + (size_t)l * 786432,
        bias_my + l * 3072, bias_op + l * 3072,
        proj_my, proj_op, 3072, 256, 0, 96);
    gat_edge<<<NGR, 256, 0, stream>>>(proj_my, proj_op, e_beats,
                                      gat_att + (l * 2 + 0) * 1024,
                                      gat_bsp + (l * 2 + 0) * 256, gat_op);
    gat_edge<<<NGR, 256, 0, stream>>>(proj_op + 1024, proj_my + 1024, e_rl,
                                      gat_att + (l * 2 + 1) * 1024,
                                      gat_bsp + (l * 2 + 1) * 256, gat_my);
    cg_edge<<<NGR, 256, 0, stream>>>(proj_op + 2048, proj_op + 2304,
                                     proj_my + 2048, proj_my + 2304,
                                     Hopp, gat_op, e_loses, ni_op);
    cg_edge<<<NGR, 256, 0, stream>>>(proj_my + 2560, proj_my + 2816,
                                     proj_op + 2560, proj_op + 2816,
                                     Hmy, gat_my, e_rb, ni_my);
    gemm128<<<dim3(192, 2), 256, 0, stream>>>(
        node_in, node_in, 256, node_wt + (size_t)l * 65536, node_wt + (size_t)l * 65536,
        node_b + l * 256, node_b + l * 256, Hb, Hb, 256, 256, 0, 192);
  }

  gemm128<<<dim3(96, 1), 256, 0, stream>>>(
      Hmy, Hmy, 256, fin_w1t, fin_w1t, fin_b1, fin_b1, fbuf, fbuf, 128, 256, 1, 96);
  logits_kernel<<<NNODES / 4, 256, 0, stream>>>(fbuf, fin_W2, fin_b2, (float*)d_out);
}

// Round 6
// 710.604 us; speedup vs baseline: 1.0094x; 1.0094x over previous
//
#include <hip/hip_runtime.h>

#define NNODES 12288
#define ETOT   73728
#define NGR    1024
#define LOG2E  1.442695041f
#define LN2    0.6931471806f

typedef __attribute__((ext_vector_type(8))) short short8;
typedef __attribute__((ext_vector_type(4))) float f32x4;

__device__ __forceinline__ unsigned short f2b(float f) {
  unsigned x = __float_as_uint(f);
  return (unsigned short)((x + 0x7FFFu + ((x >> 16) & 1u)) >> 16);
}
__device__ __forceinline__ float b2f(unsigned short u) {
  return __uint_as_float(((unsigned)u) << 16);
}
__device__ __forceinline__ void load_lds16(const void* g, void* l) {
  __builtin_amdgcn_global_load_lds(
      (const __attribute__((address_space(1))) unsigned int*)g,
      (__attribute__((address_space(3))) unsigned int*)l, 16, 0, 0);
}
__device__ __forceinline__ unsigned fenc(float f) {
  unsigned u = __float_as_uint(f);
  return (u & 0x80000000u) ? ~u : (u | 0x80000000u);
}
__device__ __forceinline__ float fdec(unsigned e) {
  unsigned u = (e & 0x80000000u) ? (e & 0x7FFFFFFFu) : ~e;
  return __uint_as_float(u);
}

// ---------------------------------------------------------------------------
// Pack: weights now in MFMA-FRAGMENT order. For a weight matrix W[n][k]
// (n = output col, k = reduction), flat layout is
//   [nblk = n>>4][kblk = k>>5][lane = (n&15) + ((k>>3)&3)*16][j = k&7]
// so one wave-load of 1KB delivers the exact 16x32 fragment. Biases, x->bf16
// unchanged.
// ---------------------------------------------------------------------------
__global__ void pack_kernel(
    const float* __restrict__ gat_Wl, const float* __restrict__ gat_Wr,
    const float* __restrict__ cg_Wf, const float* __restrict__ cg_Ws,
    const float* __restrict__ node_W, const float* __restrict__ enc_W,
    const float* __restrict__ fin_W1,
    const float* __restrict__ gat_bl, const float* __restrict__ gat_br,
    const float* __restrict__ cg_bf, const float* __restrict__ cg_bs,
    const float* __restrict__ x_my, const float* __restrict__ x_opp,
    unsigned short* __restrict__ wt_my, unsigned short* __restrict__ wt_opp,
    unsigned short* __restrict__ node_wt, unsigned short* __restrict__ enc_wt,
    unsigned short* __restrict__ fin_w1t,
    float* __restrict__ bias_my, float* __restrict__ bias_opp,
    unsigned short* __restrict__ xb)
{
  int idx = blockIdx.x * 256 + threadIdx.x;
  if (idx < 2 * 2359296) {
    int which = idx >= 2359296;
    int t = which ? idx - 2359296 : idx;
    int l = t / 786432;
    int r = t - l * 786432;
    // fragment-order inversion (KT=8)
    int j = r & 7, lane = (r >> 3) & 63, blk = r >> 9;
    int kb = blk & 7, nb = blk >> 3;
    int n = nb * 16 + (lane & 15);
    int k = kb * 32 + (lane >> 4) * 8 + j;
    float v;
    if (!which) {
      if (n < 1024)      v = gat_Wl[((l*2+0)*256 + k)*1024 + n];
      else if (n < 2048) v = gat_Wr[((l*2+1)*256 + k)*1024 + (n-1024)];
      else if (n < 2304) v = cg_Wf[((l*2+0)*512 + 256 + k)*256 + (n-2048)];
      else if (n < 2560) v = cg_Ws[((l*2+0)*512 + 256 + k)*256 + (n-2304)];
      else if (n < 2816) v = cg_Wf[((l*2+1)*512 + k)*256 + (n-2560)];
      else               v = cg_Ws[((l*2+1)*512 + k)*256 + (n-2816)];
      wt_my[t] = f2b(v);
    } else {
      if (n < 1024)      v = gat_Wr[((l*2+0)*256 + k)*1024 + n];
      else if (n < 2048) v = gat_Wl[((l*2+1)*256 + k)*1024 + (n-1024)];
      else if (n < 2304) v = cg_Wf[((l*2+0)*512 + k)*256 + (n-2048)];
      else if (n < 2560) v = cg_Ws[((l*2+0)*512 + k)*256 + (n-2304)];
      else if (n < 2816) v = cg_Wf[((l*2+1)*512 + 256 + k)*256 + (n-2560)];
      else               v = cg_Ws[((l*2+1)*512 + 256 + k)*256 + (n-2816)];
      wt_opp[t] = f2b(v);
    }
    return;
  }
  idx -= 2 * 2359296;
  if (idx < 196608) {                       // node_W fragment order (KT=8)
    int l = idx / 65536, r = idx - l * 65536;
    int j = r & 7, lane = (r >> 3) & 63, blk = r >> 9;
    int kb = blk & 7, nb = blk >> 3;
    int n = nb * 16 + (lane & 15);
    int k = kb * 32 + (lane >> 4) * 8 + j;
    node_wt[idx] = f2b(node_W[(l*256 + k)*256 + n]);
    return;
  }
  idx -= 196608;
  if (idx < 8192) {                         // enc_W fragment order (KT=1)
    int r = idx;
    int j = r & 7, lane = (r >> 3) & 63, blk = r >> 9;
    int nb = blk;                           // kb = 0
    int n = nb * 16 + (lane & 15);
    int k = (lane >> 4) * 8 + j;
    enc_wt[idx] = f2b(enc_W[k*256 + n]);
    return;
  }
  idx -= 8192;
  if (idx < 32768) {                        // fin_W1 fragment order (KT=8)
    int r = idx;
    int j = r & 7, lane = (r >> 3) & 63, blk = r >> 9;
    int kb = blk & 7, nb = blk >> 3;
    int n = nb * 16 + (lane & 15);
    int k = kb * 32 + (lane >> 4) * 8 + j;
    fin_w1t[idx] = f2b(fin_W1[k*128 + n]);
    return;
  }
  idx -= 32768;
  if (idx < 9216) {
    int l = idx / 3072, n = idx - l * 3072;
    float v;
    if (n < 1024)      v = gat_bl[(l*2+0)*1024 + n];
    else if (n < 2048) v = gat_br[(l*2+1)*1024 + (n-1024)];
    else if (n < 2560) v = 0.f;
    else if (n < 2816) v = cg_bf[(l*2+1)*256 + (n-2560)];
    else               v = cg_bs[(l*2+1)*256 + (n-2816)];
    bias_my[idx] = v;
    return;
  }
  idx -= 9216;
  if (idx < 9216) {
    int l = idx / 3072, n = idx - l * 3072;
    float v;
    if (n < 1024)      v = gat_br[(l*2+0)*1024 + n];
    else if (n < 2048) v = gat_bl[(l*2+1)*1024 + (n-1024)];
    else if (n < 2304) v = cg_bf[(l*2+0)*256 + (n-2048)];
    else if (n < 2560) v = cg_bs[(l*2+0)*256 + (n-2304)];
    else               v = 0.f;
    bias_opp[idx] = v;
    return;
  }
  idx -= 9216;
  if (idx < 2 * 393216) {
    xb[idx] = f2b(idx < 393216 ? x_my[idx] : x_opp[idx - 393216]);
  }
}

// ---------------------------------------------------------------------------
// bf16 GEMM v4 "gemm64": BM=64, BN=128, full-K A in LDS (<=32KB), staged ONCE
// (granule-XOR-swizzled source, linear dest), ONE barrier per block; k-loop is
// barrier-free: B-fragments loaded coalesced from fragment-packed global W
// (prefetched 1 k-step ahead), A-fragments via conflict-free ds_read_b128.
// 4 waves (2M x 2N), acc 2x4, ~100 VGPR -> ~5 blocks/CU of independent waves.
// ---------------------------------------------------------------------------
__global__ __launch_bounds__(256) void gemm64(
    const unsigned short* __restrict__ A, const unsigned short* __restrict__ Ab,
    int lda,
    const unsigned short* __restrict__ Wp, const unsigned short* __restrict__ Wpb,
    const float* __restrict__ bias, const float* __restrict__ biasb,
    unsigned short* __restrict__ C, unsigned short* __restrict__ Cb,
    int ldc, int K, int act, int bx_split)
{
  __shared__ __align__(16) unsigned short lA[64 * 256];
  const int tid = threadIdx.x;
  const int lane = tid & 63;
  const int w = tid >> 6;
  const int wr = w >> 1, wc = w & 1;
  const int r0 = lane & 15, kq = lane >> 4;
  const int KT = K >> 5;
  const int gm = (K >> 3) - 1;              // granule index mask within a row
  const int rmask = gm > 7 ? 7 : gm;        // row-XOR swizzle mask
  const int gsh = __popc((unsigned)gm);     // log2(K/8)

  const unsigned short *Ap, *Wsel;
  const float* bp;
  unsigned short* Cp;
  int tileM;
  if ((int)blockIdx.x < bx_split) {
    Ap = A;  Wsel = Wp;  bp = bias;  Cp = C;  tileM = blockIdx.x * 64;
  } else {
    Ap = Ab; Wsel = Wpb; bp = biasb; Cp = Cb; tileM = (blockIdx.x - bx_split) * 64;
  }
  const int tileN = blockIdx.y * 128;

  // stage full-K A tile (KT rounds of 256 threads x 16B)
  for (int rd = 0; rd < KT; ++rd) {
    int idx = rd * 256 + tid;
    int row = idx >> gsh;
    int g = idx & gm;
    load_lds16(Ap + (size_t)(tileM + row) * lda + ((g ^ (row & rmask)) << 3),
               (char*)lA + idx * 16);
  }

  // fragment-packed W pointers (coalesced: 64 lanes x 16B = 1KB per fragment)
  const int nblk0 = (tileN >> 4) + wc * 4;
  const unsigned short* wn0 = Wsel + ((size_t)(nblk0 + 0) * KT * 64 + lane) * 8;
  const unsigned short* wn1 = Wsel + ((size_t)(nblk0 + 1) * KT * 64 + lane) * 8;
  const unsigned short* wn2 = Wsel + ((size_t)(nblk0 + 2) * KT * 64 + lane) * 8;
  const unsigned short* wn3 = Wsel + ((size_t)(nblk0 + 3) * KT * 64 + lane) * 8;

  // issue k-step-0 B loads before the barrier (overlap the A-stage wait)
  short8 bc0 = *(const short8*)wn0;
  short8 bc1 = *(const short8*)wn1;
  short8 bc2 = *(const short8*)wn2;
  short8 bc3 = *(const short8*)wn3;

  f32x4 acc[2][4];
#pragma unroll
  for (int m = 0; m < 2; ++m)
#pragma unroll
    for (int n = 0; n < 4; ++n)
      acc[m][n] = (f32x4){0.f, 0.f, 0.f, 0.f};

  const int rb0 = (wr * 32 + r0) * K;
  const int rb1 = (wr * 32 + 16 + r0) * K;
  const int rx = r0 & rmask;

  __syncthreads();   // single barrier: A tile (and bc*) resident

  for (int kt = 0; kt < KT; ++kt) {
    short8 bn0 = bc0, bn1 = bc1, bn2 = bc2, bn3 = bc3;
    if (kt + 1 < KT) {
      const int o = (kt + 1) * 512;
      bn0 = *(const short8*)(wn0 + o);
      bn1 = *(const short8*)(wn1 + o);
      bn2 = *(const short8*)(wn2 + o);
      bn3 = *(const short8*)(wn3 + o);
    }
    const int p = (((kt << 2) + kq) ^ rx) * 8;
    short8 af0 = *(const short8*)&lA[rb0 + p];
    short8 af1 = *(const short8*)&lA[rb1 + p];
    acc[0][0] = __builtin_amdgcn_mfma_f32_16x16x32_bf16(bc0, af0, acc[0][0], 0, 0, 0);
    acc[0][1] = __builtin_amdgcn_mfma_f32_16x16x32_bf16(bc1, af0, acc[0][1], 0, 0, 0);
    acc[0][2] = __builtin_amdgcn_mfma_f32_16x16x32_bf16(bc2, af0, acc[0][2], 0, 0, 0);
    acc[0][3] = __builtin_amdgcn_mfma_f32_16x16x32_bf16(bc3, af0, acc[0][3], 0, 0, 0);
    acc[1][0] = __builtin_amdgcn_mfma_f32_16x16x32_bf16(bc0, af1, acc[1][0], 0, 0, 0);
    acc[1][1] = __builtin_amdgcn_mfma_f32_16x16x32_bf16(bc1, af1, acc[1][1], 0, 0, 0);
    acc[1][2] = __builtin_amdgcn_mfma_f32_16x16x32_bf16(bc2, af1, acc[1][2], 0, 0, 0);
    acc[1][3] = __builtin_amdgcn_mfma_f32_16x16x32_bf16(bc3, af1, acc[1][3], 0, 0, 0);
    bc0 = bn0; bc1 = bn1; bc2 = bn2; bc3 = bn3;
  }

  // epilogue: lane owns rows (tileM + wr*32 + m*16 + r0), 4 consecutive cols
#pragma unroll
  for (int m = 0; m < 2; ++m) {
    const int row = tileM + wr * 32 + m * 16 + r0;
    unsigned short* crow = Cp + (size_t)row * ldc;
#pragma unroll
    for (int n = 0; n < 4; ++n) {
      const int col0 = tileN + wc * 64 + n * 16 + kq * 4;
      const f32x4 bv = *(const f32x4*)&bp[col0];
      float v0 = acc[m][n][0] + bv[0];
      float v1 = acc[m][n][1] + bv[1];
      float v2 = acc[m][n][2] + bv[2];
      float v3 = acc[m][n][3] + bv[3];
      if (act) {
        v0 = v0 > 0.f ? v0 : 128.f * v0;
        v1 = v1 > 0.f ? v1 : 128.f * v1;
        v2 = v2 > 0.f ? v2 : 128.f * v2;
        v3 = v3 > 0.f ? v3 : 128.f * v3;
      }
      uint2 pk;
      pk.x = (unsigned)f2b(v0) | ((unsigned)f2b(v1) << 16);
      pk.y = (unsigned)f2b(v2) | ((unsigned)f2b(v3) << 16);
      *(uint2*)(crow + col0) = pk;
    }
  }
}

// ---------------------------------------------------------------------------
// GATv2 edge stage (unchanged): edge-parallel softmax, LDS atomics.
// ---------------------------------------------------------------------------
#define SX 260
__global__ __launch_bounds__(256) void gat_edge(
    const unsigned short* __restrict__ projS,
    const unsigned short* __restrict__ projD,
    const int* __restrict__ edges,
    const float* __restrict__ att,
    const float* __restrict__ gbias,
    float* __restrict__ outp)
{
  __shared__ __align__(16) unsigned short xl[48 * SX];
  __shared__ float attS[4 * SX];
  __shared__ float alphaS[288];
  __shared__ float wS[288];
  __shared__ unsigned mU[48];
  __shared__ float denS[48];
  __shared__ __align__(16) float A2f[12 * 48];
  __shared__ unsigned char se8[72], de8[72];
  const int g = blockIdx.x, tid = threadIdx.x;
  const int base = g * 12;

  if (tid < 72) {
    se8[tid] = (unsigned char)(edges[g * 72 + tid] - base);
    de8[tid] = (unsigned char)(edges[ETOT + g * 72 + tid] - base);
  }
  if (tid < 48) { mU[tid] = 0u; denS[tid] = 0.f; }
  for (int i = tid; i < 576; i += 256) A2f[i] = 0.f;
  for (int i = tid; i < 1024; i += 256)
    attS[(i >> 8) * SX + (i & 255)] = att[i];
  for (int i = tid; i < 3072; i += 256) {
    int s = i >> 8, c4 = (i & 255) * 4;
    int h = c4 >> 8, cc = c4 & 255;
    *(ushort4*)&xl[(h * 12 + s) * SX + cc] =
        *(const ushort4*)(projS + (size_t)(base + s) * 3072 + c4);
  }
  __syncthreads();

  for (int t = tid; t < 288; t += 256) {
    const int e = t >> 2, h = t & 3;
    const unsigned short* pl = &xl[(h * 12 + se8[e]) * SX];
    const unsigned short* pr = projD + (size_t)(base + de8[e]) * 3072 + h * 256;
    const f32x4* pa = (const f32x4*)&attS[h * SX];
    float sum = 0.f;
    for (int q = 0; q < 64; ++q) {
      ushort4 a4 = *(const ushort4*)(pl + q * 4);
      ushort4 b4 = *(const ushort4*)(pr + q * 4);
      f32x4 av = pa[q];
      float v0 = b2f(a4.x) + b2f(b4.x); v0 = fmaxf(v0, 0.2f * v0);
      float v1 = b2f(a4.y) + b2f(b4.y); v1 = fmaxf(v1, 0.2f * v1);
      float v2 = b2f(a4.z) + b2f(b4.z); v2 = fmaxf(v2, 0.2f * v2);
      float v3 = b2f(a4.w) + b2f(b4.w); v3 = fmaxf(v3, 0.2f * v3);
      sum = fmaf(v0, av.x, sum); sum = fmaf(v1, av.y, sum);
      sum = fmaf(v2, av.z, sum); sum = fmaf(v3, av.w, sum);
    }
    sum *= LOG2E;
    alphaS[t] = sum;
    atomicMax(&mU[de8[e] * 4 + h], fenc(sum));
  }
  __syncthreads();

  for (int t = tid; t < 288; t += 256) {
    const int e = t >> 2, h = t & 3;
    const float m = fdec(mU[de8[e] * 4 + h]);
    const float wv = __builtin_amdgcn_exp2f(alphaS[t] - m);
    wS[t] = wv;
    atomicAdd(&denS[de8[e] * 4 + h], wv);
  }
  __syncthreads();

  for (int t = tid; t < 288; t += 256) {
    const int e = t >> 2, h = t & 3;
    const float inv = 0.25f * __builtin_amdgcn_rcpf(denS[de8[e] * 4 + h] + 1e-16f);
    atomicAdd(&A2f[de8[e] * 48 + h * 12 + se8[e]], wS[t] * inv);
  }
  __syncthreads();

  {
    const int c = tid;
    float xlv[48];
#pragma unroll
    for (int j = 0; j < 48; ++j) xlv[j] = b2f(xl[j * SX + c]);
    const float gb = gbias[c];
#pragma unroll
    for (int d = 0; d < 12; ++d) {
      const f32x4* arow = (const f32x4*)&A2f[d * 48];
      float s = 0.f;
#pragma unroll
      for (int jj = 0; jj < 12; ++jj) {
        f32x4 a4 = arow[jj];
        s = fmaf(a4.x, xlv[jj * 4 + 0], s);
        s = fmaf(a4.y, xlv[jj * 4 + 1], s);
        s = fmaf(a4.z, xlv[jj * 4 + 2], s);
        s = fmaf(a4.w, xlv[jj * 4 + 3], s);
      }
      outp[(size_t)(base + d) * 256 + c] = s + gb;
    }
  }
}

// ---------------------------------------------------------------------------
// CGConv edge stage (unchanged).
// ---------------------------------------------------------------------------
__global__ __launch_bounds__(256) void cg_edge(
    const unsigned short* __restrict__ pdF, const unsigned short* __restrict__ pdS,
    const unsigned short* __restrict__ psF, const unsigned short* __restrict__ psS,
    const unsigned short* __restrict__ hres,
    const float* __restrict__ gatp,
    const int* __restrict__ edges,
    unsigned short* __restrict__ outp)
{
  __shared__ __align__(8) unsigned short df[3072], dsb[3072];
  __shared__ __align__(8) unsigned short sfb[3072], ssb[3072];
  __shared__ unsigned char srcl[12 * 80];
  __shared__ int cnt[12];
  __shared__ int se_[72], de_[72];
  const int g = blockIdx.x, tid = threadIdx.x;
  const int base = g * 12;
  if (tid < 72) {
    se_[tid] = edges[g * 72 + tid] - base;
    de_[tid] = edges[ETOT + g * 72 + tid] - base;
  }
  for (int i = tid; i < 768; i += 256) {
    int s = i >> 6, c4 = (i & 63) * 4;
    size_t gb = (size_t)(base + s) * 3072 + c4;
    *(ushort4*)&df[s * 256 + c4]  = *(const ushort4*)(pdF + gb);
    *(ushort4*)&dsb[s * 256 + c4] = *(const ushort4*)(pdS + gb);
    *(ushort4*)&sfb[s * 256 + c4] = *(const ushort4*)(psF + gb);
    *(ushort4*)&ssb[s * 256 + c4] = *(const ushort4*)(psS + gb);
  }
  __syncthreads();
  if (tid < 12) {
    int n = 0;
    for (int e = 0; e < 72; ++e)
      if (de_[e] == tid) srcl[tid * 80 + (n++)] = (unsigned char)se_[e];
    cnt[tid] = n;
  }
  __syncthreads();
  const int c = tid;
  for (int d = 0; d < 12; ++d) {
    const float fd = b2f(df[d * 256 + c]);
    const float sd = b2f(dsb[d * 256 + c]);
    const int n = cnt[d];
    float acc = 0.f;
    for (int j = 0; j < n; ++j) {
      const int s = srcl[d * 80 + j];
      const float zf = fd + b2f(sfb[s * 256 + c]);
      const float zs = sd + b2f(ssb[s * 256 + c]);
      const float gate = __builtin_amdgcn_rcpf(1.f + __builtin_amdgcn_exp2f(-LOG2E * zf));
      const float e2 = __builtin_amdgcn_exp2f(-LOG2E * fabsf(zs));
      const float sp = fmaxf(zs, 0.f) + LN2 * __builtin_amdgcn_logf(1.f + e2);
      acc = fmaf(gate, sp, acc);
    }
    const size_t o = (size_t)(base + d) * 256 + c;
    outp[o] = f2b(b2f(hres[o]) + gatp[o] + acc);
  }
}

// ---------------------------------------------------------------------------
// logits: one wave per node, dot(f[128], W2) + b2
// ---------------------------------------------------------------------------
__global__ __launch_bounds__(256) void logits_kernel(
    const unsigned short* __restrict__ f, const float* __restrict__ W2,
    const float* __restrict__ b2, float* __restrict__ out)
{
  const int node = blockIdx.x * 4 + (threadIdx.x >> 6);
  const int lane = threadIdx.x & 63;
  const size_t o = (size_t)node * 128 + lane * 2;
  float s = b2f(f[o]) * W2[lane * 2] + b2f(f[o + 1]) * W2[lane * 2 + 1];
  for (int d = 32; d > 0; d >>= 1) s += __shfl_down(s, d, 64);
  if (lane == 0) out[node] = s + b2[0];
}

// ---------------------------------------------------------------------------
extern "C" void kernel_launch(void* const* d_in, const int* in_sizes, int n_in,
                              void* d_out, int out_size, void* d_ws, size_t ws_size,
                              hipStream_t stream) {
  const float* x_my    = (const float*)d_in[0];
  const float* x_opp   = (const float*)d_in[1];
  const int*   e_beats = (const int*)d_in[2];
  const int*   e_loses = (const int*)d_in[3];
  const int*   e_rb    = (const int*)d_in[4];
  const int*   e_rl    = (const int*)d_in[5];
  const float* enc_W   = (const float*)d_in[7];
  const float* enc_b   = (const float*)d_in[8];
  const float* gat_Wl  = (const float*)d_in[9];
  const float* gat_bl  = (const float*)d_in[10];
  const float* gat_Wr  = (const float*)d_in[11];
  const float* gat_br  = (const float*)d_in[12];
  const float* gat_att = (const float*)d_in[13];
  const float* gat_bsp = (const float*)d_in[14];
  const float* cg_Wf   = (const float*)d_in[15];
  const float* cg_bf   = (const float*)d_in[16];
  const float* cg_Ws   = (const float*)d_in[17];
  const float* cg_bs   = (const float*)d_in[18];
  const float* node_W  = (const float*)d_in[19];
  const float* node_b  = (const float*)d_in[20];
  const float* fin_W1  = (const float*)d_in[21];
  const float* fin_b1  = (const float*)d_in[22];
  const float* fin_W2  = (const float*)d_in[23];
  const float* fin_b2  = (const float*)d_in[24];

  char* wsp = (char*)d_ws;
  size_t off = 0;
  auto alloc = [&](size_t b) { char* p = wsp + off; off += (b + 255) & ~(size_t)255; return p; };
  unsigned short* wt_my   = (unsigned short*)alloc((size_t)2359296 * 2);
  unsigned short* wt_opp  = (unsigned short*)alloc((size_t)2359296 * 2);
  unsigned short* node_wt = (unsigned short*)alloc((size_t)196608 * 2);
  unsigned short* enc_wt  = (unsigned short*)alloc((size_t)8192 * 2);
  unsigned short* fin_w1t = (unsigned short*)alloc((size_t)32768 * 2);
  float*          bias_my = (float*)alloc((size_t)9216 * 4);
  float*          bias_op = (float*)alloc((size_t)9216 * 4);
  unsigned short* xb      = (unsigned short*)alloc((size_t)786432 * 2);
  unsigned short* Hb      = (unsigned short*)alloc((size_t)2 * NNODES * 256 * 2);
  unsigned short* proj_my = (unsigned short*)alloc((size_t)NNODES * 3072 * 2);
  unsigned short* proj_op = (unsigned short*)alloc((size_t)NNODES * 3072 * 2);
  float*          gat_my  = (float*)alloc((size_t)NNODES * 256 * 4);
  float*          gat_op  = (float*)alloc((size_t)NNODES * 256 * 4);
  unsigned short* node_in = (unsigned short*)alloc((size_t)2 * NNODES * 256 * 2);
  unsigned short* fbuf    = (unsigned short*)alloc((size_t)NNODES * 128 * 2);

  const int PACK_TOTAL = 2 * 2359296 + 196608 + 8192 + 32768 + 2 * 9216 + 2 * 393216;
  pack_kernel<<<(PACK_TOTAL + 255) / 256, 256, 0, stream>>>(
      gat_Wl, gat_Wr, cg_Wf, cg_Ws, node_W, enc_W, fin_W1,
      gat_bl, gat_br, cg_bf, cg_bs, x_my, x_opp,
      wt_my, wt_opp, node_wt, enc_wt, fin_w1t, bias_my, bias_op, xb);

  unsigned short* Hmy   = Hb;
  unsigned short* Hopp  = Hb + (size_t)NNODES * 256;
  unsigned short* ni_my = node_in;
  unsigned short* ni_op = node_in + (size_t)NNODES * 256;

  // encoder: h = x @ enc_W + enc_b  (M = 24576, N = 256, K = 32)
  gemm64<<<dim3(384, 2), 256, 0, stream>>>(
      xb, xb, 32, enc_wt, enc_wt, enc_b, enc_b, Hb, Hb, 256, 32, 0, 384);

  for (int l = 0; l < 3; ++l) {
    // both proj GEMMs in one dispatch (x-blocks 0..191 = my, 192..383 = opp)
    gemm64<<<dim3(384, 24), 256, 0, stream>>>(
        Hmy, Hopp, 256,
        wt_my + (size_t)l * 786432, wt_opp + (size_t)l * 786432,
        bias_my + l * 3072, bias_op + l * 3072,
        proj_my, proj_op, 3072, 256, 0, 192);
    gat_edge<<<NGR, 256, 0, stream>>>(proj_my, proj_op, e_beats,
                                      gat_att + (l * 2 + 0) * 1024,
                                      gat_bsp + (l * 2 + 0) * 256, gat_op);
    gat_edge<<<NGR, 256, 0, stream>>>(proj_op + 1024, proj_my + 1024, e_rl,
                                      gat_att + (l * 2 + 1) * 1024,
                                      gat_bsp + (l * 2 + 1) * 256, gat_my);
    cg_edge<<<NGR, 256, 0, stream>>>(proj_op + 2048, proj_op + 2304,
                                     proj_my + 2048, proj_my + 2304,
                                     Hopp, gat_op, e_loses, ni_op);
    cg_edge<<<NGR, 256, 0, stream>>>(proj_my + 2560, proj_my + 2816,
                                     proj_op + 2560, proj_op + 2816,
                                     Hmy, gat_my, e_rb, ni_my);
    // node linear (both types contiguous, M = 24576, N = 256, K = 256)
    gemm64<<<dim3(384, 2), 256, 0, stream>>>(
        node_in, node_in, 256, node_wt + (size_t)l * 65536, node_wt + (size_t)l * 65536,
        node_b + l * 256, node_b + l * 256, Hb, Hb, 256, 256, 0, 384);
  }

  // final encoder: f = leaky_relu(h_my @ W1 + b1, 128)  (M=12288, N=128, K=256)
  gemm64<<<dim3(192, 1), 256, 0, stream>>>(
      Hmy, Hmy, 256, fin_w1t, fin_w1t, fin_b1, fin_b1, fbuf, fbuf, 128, 256, 1, 192);
  logits_kernel<<<NNODES / 4, 256, 0, stream>>>(fbuf, fin_W2, fin_b2, (float*)d_out);
}

// Round 7
// 641.068 us; speedup vs baseline: 1.1188x; 1.1085x over previous
//
#include <hip/hip_runtime.h>

#define NNODES 12288
#define ETOT   73728
#define NGR    1024
#define LOG2E  1.442695041f
#define LN2    0.6931471806f

typedef __attribute__((ext_vector_type(8))) short short8;
typedef __attribute__((ext_vector_type(4))) float f32x4;

__device__ __forceinline__ unsigned short f2b(float f) {
  unsigned x = __float_as_uint(f);
  return (unsigned short)((x + 0x7FFFu + ((x >> 16) & 1u)) >> 16);
}
__device__ __forceinline__ float b2f(unsigned short u) {
  return __uint_as_float(((unsigned)u) << 16);
}
__device__ __forceinline__ void load_lds16(const void* g, void* l) {
  __builtin_amdgcn_global_load_lds(
      (const __attribute__((address_space(1))) unsigned int*)g,
      (__attribute__((address_space(3))) unsigned int*)l, 16, 0, 0);
}
__device__ __forceinline__ unsigned fenc(float f) {
  unsigned u = __float_as_uint(f);
  return (u & 0x80000000u) ? ~u : (u | 0x80000000u);
}
__device__ __forceinline__ float fdec(unsigned e) {
  unsigned u = (e & 0x80000000u) ? (e & 0x7FFFFFFFu) : ~e;
  return __uint_as_float(u);
}

// ---------------------------------------------------------------------------
// Pack (unchanged from R5): weights in MFMA-fragment order
//   [nblk][kblk][lane=(n&15)+((k>>3)&3)*16][j=k&7]
// ---------------------------------------------------------------------------
__global__ void pack_kernel(
    const float* __restrict__ gat_Wl, const float* __restrict__ gat_Wr,
    const float* __restrict__ cg_Wf, const float* __restrict__ cg_Ws,
    const float* __restrict__ node_W, const float* __restrict__ enc_W,
    const float* __restrict__ fin_W1,
    const float* __restrict__ gat_bl, const float* __restrict__ gat_br,
    const float* __restrict__ cg_bf, const float* __restrict__ cg_bs,
    const float* __restrict__ x_my, const float* __restrict__ x_opp,
    unsigned short* __restrict__ wt_my, unsigned short* __restrict__ wt_opp,
    unsigned short* __restrict__ node_wt, unsigned short* __restrict__ enc_wt,
    unsigned short* __restrict__ fin_w1t,
    float* __restrict__ bias_my, float* __restrict__ bias_opp,
    unsigned short* __restrict__ xb)
{
  int idx = blockIdx.x * 256 + threadIdx.x;
  if (idx < 2 * 2359296) {
    int which = idx >= 2359296;
    int t = which ? idx - 2359296 : idx;
    int l = t / 786432;
    int r = t - l * 786432;
    int j = r & 7, lane = (r >> 3) & 63, blk = r >> 9;
    int kb = blk & 7, nb = blk >> 3;
    int n = nb * 16 + (lane & 15);
    int k = kb * 32 + (lane >> 4) * 8 + j;
    float v;
    if (!which) {
      if (n < 1024)      v = gat_Wl[((l*2+0)*256 + k)*1024 + n];
      else if (n < 2048) v = gat_Wr[((l*2+1)*256 + k)*1024 + (n-1024)];
      else if (n < 2304) v = cg_Wf[((l*2+0)*512 + 256 + k)*256 + (n-2048)];
      else if (n < 2560) v = cg_Ws[((l*2+0)*512 + 256 + k)*256 + (n-2304)];
      else if (n < 2816) v = cg_Wf[((l*2+1)*512 + k)*256 + (n-2560)];
      else               v = cg_Ws[((l*2+1)*512 + k)*256 + (n-2816)];
      wt_my[t] = f2b(v);
    } else {
      if (n < 1024)      v = gat_Wr[((l*2+0)*256 + k)*1024 + n];
      else if (n < 2048) v = gat_Wl[((l*2+1)*256 + k)*1024 + (n-1024)];
      else if (n < 2304) v = cg_Wf[((l*2+0)*512 + k)*256 + (n-2048)];
      else if (n < 2560) v = cg_Ws[((l*2+0)*512 + k)*256 + (n-2304)];
      else if (n < 2816) v = cg_Wf[((l*2+1)*512 + 256 + k)*256 + (n-2560)];
      else               v = cg_Ws[((l*2+1)*512 + 256 + k)*256 + (n-2816)];
      wt_opp[t] = f2b(v);
    }
    return;
  }
  idx -= 2 * 2359296;
  if (idx < 196608) {
    int l = idx / 65536, r = idx - l * 65536;
    int j = r & 7, lane = (r >> 3) & 63, blk = r >> 9;
    int kb = blk & 7, nb = blk >> 3;
    int n = nb * 16 + (lane & 15);
    int k = kb * 32 + (lane >> 4) * 8 + j;
    node_wt[idx] = f2b(node_W[(l*256 + k)*256 + n]);
    return;
  }
  idx -= 196608;
  if (idx < 8192) {
    int r = idx;
    int j = r & 7, lane = (r >> 3) & 63, blk = r >> 9;
    int nb = blk;
    int n = nb * 16 + (lane & 15);
    int k = (lane >> 4) * 8 + j;
    enc_wt[idx] = f2b(enc_W[k*256 + n]);
    return;
  }
  idx -= 8192;
  if (idx < 32768) {
    int r = idx;
    int j = r & 7, lane = (r >> 3) & 63, blk = r >> 9;
    int kb = blk & 7, nb = blk >> 3;
    int n = nb * 16 + (lane & 15);
    int k = kb * 32 + (lane >> 4) * 8 + j;
    fin_w1t[idx] = f2b(fin_W1[k*128 + n]);
    return;
  }
  idx -= 32768;
  if (idx < 9216) {
    int l = idx / 3072, n = idx - l * 3072;
    float v;
    if (n < 1024)      v = gat_bl[(l*2+0)*1024 + n];
    else if (n < 2048) v = gat_br[(l*2+1)*1024 + (n-1024)];
    else if (n < 2560) v = 0.f;
    else if (n < 2816) v = cg_bf[(l*2+1)*256 + (n-2560)];
    else               v = cg_bs[(l*2+1)*256 + (n-2816)];
    bias_my[idx] = v;
    return;
  }
  idx -= 9216;
  if (idx < 9216) {
    int l = idx / 3072, n = idx - l * 3072;
    float v;
    if (n < 1024)      v = gat_br[(l*2+0)*1024 + n];
    else if (n < 2048) v = gat_bl[(l*2+1)*1024 + (n-1024)];
    else if (n < 2304) v = cg_bf[(l*2+0)*256 + (n-2048)];
    else if (n < 2560) v = cg_bs[(l*2+0)*256 + (n-2304)];
    else               v = 0.f;
    bias_opp[idx] = v;
    return;
  }
  idx -= 9216;
  if (idx < 2 * 393216) {
    xb[idx] = f2b(idx < 393216 ? x_my[idx] : x_opp[idx - 393216]);
  }
}

// ---------------------------------------------------------------------------
// bf16 GEMM v5: R5's gemm64 (full-K A staged once, barrier-free k-loop,
// fragment-packed global W) + LDS-STAGED COALESCED EPILOGUE: acc -> padded
// 64x132 LDS C-tile (bf16), then row-major dwordx4 stores (4 rows x 256B
// contiguous per wave-instr) instead of 16x scattered 8B segments.
// ---------------------------------------------------------------------------
__global__ __launch_bounds__(256) void gemm64(
    const unsigned short* __restrict__ A, const unsigned short* __restrict__ Ab,
    int lda,
    const unsigned short* __restrict__ Wp, const unsigned short* __restrict__ Wpb,
    const float* __restrict__ bias, const float* __restrict__ biasb,
    unsigned short* __restrict__ C, unsigned short* __restrict__ Cb,
    int ldc, int K, int act, int bx_split)
{
  __shared__ __align__(16) unsigned short lA[64 * 256];
  const int tid = threadIdx.x;
  const int lane = tid & 63;
  const int w = tid >> 6;
  const int wr = w >> 1, wc = w & 1;
  const int r0 = lane & 15, kq = lane >> 4;
  const int KT = K >> 5;
  const int gm = (K >> 3) - 1;
  const int rmask = gm > 7 ? 7 : gm;
  const int gsh = __popc((unsigned)gm);

  const unsigned short *Ap, *Wsel;
  const float* bp;
  unsigned short* Cp;
  int tileM;
  if ((int)blockIdx.x < bx_split) {
    Ap = A;  Wsel = Wp;  bp = bias;  Cp = C;  tileM = blockIdx.x * 64;
  } else {
    Ap = Ab; Wsel = Wpb; bp = biasb; Cp = Cb; tileM = (blockIdx.x - bx_split) * 64;
  }
  const int tileN = blockIdx.y * 128;

  for (int rd = 0; rd < KT; ++rd) {
    int idx = rd * 256 + tid;
    int row = idx >> gsh;
    int g = idx & gm;
    load_lds16(Ap + (size_t)(tileM + row) * lda + ((g ^ (row & rmask)) << 3),
               (char*)lA + idx * 16);
  }

  const int nblk0 = (tileN >> 4) + wc * 4;
  const unsigned short* wn0 = Wsel + ((size_t)(nblk0 + 0) * KT * 64 + lane) * 8;
  const unsigned short* wn1 = Wsel + ((size_t)(nblk0 + 1) * KT * 64 + lane) * 8;
  const unsigned short* wn2 = Wsel + ((size_t)(nblk0 + 2) * KT * 64 + lane) * 8;
  const unsigned short* wn3 = Wsel + ((size_t)(nblk0 + 3) * KT * 64 + lane) * 8;

  short8 bc0 = *(const short8*)wn0;
  short8 bc1 = *(const short8*)wn1;
  short8 bc2 = *(const short8*)wn2;
  short8 bc3 = *(const short8*)wn3;

  f32x4 acc[2][4];
#pragma unroll
  for (int m = 0; m < 2; ++m)
#pragma unroll
    for (int n = 0; n < 4; ++n)
      acc[m][n] = (f32x4){0.f, 0.f, 0.f, 0.f};

  const int rb0 = (wr * 32 + r0) * K;
  const int rb1 = (wr * 32 + 16 + r0) * K;
  const int rx = r0 & rmask;

  __syncthreads();   // A tile resident

  for (int kt = 0; kt < KT; ++kt) {
    short8 bn0 = bc0, bn1 = bc1, bn2 = bc2, bn3 = bc3;
    if (kt + 1 < KT) {
      const int o = (kt + 1) * 512;
      bn0 = *(const short8*)(wn0 + o);
      bn1 = *(const short8*)(wn1 + o);
      bn2 = *(const short8*)(wn2 + o);
      bn3 = *(const short8*)(wn3 + o);
    }
    const int p = (((kt << 2) + kq) ^ rx) * 8;
    short8 af0 = *(const short8*)&lA[rb0 + p];
    short8 af1 = *(const short8*)&lA[rb1 + p];
    acc[0][0] = __builtin_amdgcn_mfma_f32_16x16x32_bf16(bc0, af0, acc[0][0], 0, 0, 0);
    acc[0][1] = __builtin_amdgcn_mfma_f32_16x16x32_bf16(bc1, af0, acc[0][1], 0, 0, 0);
    acc[0][2] = __builtin_amdgcn_mfma_f32_16x16x32_bf16(bc2, af0, acc[0][2], 0, 0, 0);
    acc[0][3] = __builtin_amdgcn_mfma_f32_16x16x32_bf16(bc3, af0, acc[0][3], 0, 0, 0);
    acc[1][0] = __builtin_amdgcn_mfma_f32_16x16x32_bf16(bc0, af1, acc[1][0], 0, 0, 0);
    acc[1][1] = __builtin_amdgcn_mfma_f32_16x16x32_bf16(bc1, af1, acc[1][1], 0, 0, 0);
    acc[1][2] = __builtin_amdgcn_mfma_f32_16x16x32_bf16(bc2, af1, acc[1][2], 0, 0, 0);
    acc[1][3] = __builtin_amdgcn_mfma_f32_16x16x32_bf16(bc3, af1, acc[1][3], 0, 0, 0);
    bc0 = bn0; bc1 = bn1; bc2 = bn2; bc3 = bn3;
  }

  // ---- coalesced epilogue: stage bf16 C-tile in LDS (stride 132), then
  // row-major dwordx4 stores (each wave: 4 rows x 256B contiguous) ----
  unsigned short* cT = lA;                   // reuse staging LDS (64*132 <= 64*256)
  __syncthreads();                           // all k-loop LDS reads done
#pragma unroll
  for (int m = 0; m < 2; ++m) {
    const int rl = wr * 32 + m * 16 + r0;
#pragma unroll
    for (int n = 0; n < 4; ++n) {
      const int cl = wc * 64 + n * 16 + kq * 4;
      const f32x4 bv = *(const f32x4*)&bp[tileN + cl];
      float v0 = acc[m][n][0] + bv[0];
      float v1 = acc[m][n][1] + bv[1];
      float v2 = acc[m][n][2] + bv[2];
      float v3 = acc[m][n][3] + bv[3];
      if (act) {
        v0 = v0 > 0.f ? v0 : 128.f * v0;
        v1 = v1 > 0.f ? v1 : 128.f * v1;
        v2 = v2 > 0.f ? v2 : 128.f * v2;
        v3 = v3 > 0.f ? v3 : 128.f * v3;
      }
      uint2 pk;
      pk.x = (unsigned)f2b(v0) | ((unsigned)f2b(v1) << 16);
      pk.y = (unsigned)f2b(v2) | ((unsigned)f2b(v3) << 16);
      *(uint2*)&cT[rl * 132 + cl] = pk;
    }
  }
  __syncthreads();
  // 64 rows x 128 cols -> 1024 x 16B chunks; idx>>4 = row, idx&15 = chunk
#pragma unroll
  for (int it = 0; it < 4; ++it) {
    const int idx = it * 256 + tid;
    const int row = idx >> 4, ch = idx & 15;
    const uint4 val = *(const uint4*)&cT[row * 132 + ch * 8];
    *(uint4*)(Cp + (size_t)(tileM + row) * ldc + tileN + ch * 8) = val;
  }
}

// ---------------------------------------------------------------------------
// GATv2 edge stage (unchanged): edge-parallel softmax, LDS atomics.
// ---------------------------------------------------------------------------
#define SX 260
__global__ __launch_bounds__(256) void gat_edge(
    const unsigned short* __restrict__ projS,
    const unsigned short* __restrict__ projD,
    const int* __restrict__ edges,
    const float* __restrict__ att,
    const float* __restrict__ gbias,
    float* __restrict__ outp)
{
  __shared__ __align__(16) unsigned short xl[48 * SX];
  __shared__ float attS[4 * SX];
  __shared__ float alphaS[288];
  __shared__ float wS[288];
  __shared__ unsigned mU[48];
  __shared__ float denS[48];
  __shared__ __align__(16) float A2f[12 * 48];
  __shared__ unsigned char se8[72], de8[72];
  const int g = blockIdx.x, tid = threadIdx.x;
  const int base = g * 12;

  if (tid < 72) {
    se8[tid] = (unsigned char)(edges[g * 72 + tid] - base);
    de8[tid] = (unsigned char)(edges[ETOT + g * 72 + tid] - base);
  }
  if (tid < 48) { mU[tid] = 0u; denS[tid] = 0.f; }
  for (int i = tid; i < 576; i += 256) A2f[i] = 0.f;
  for (int i = tid; i < 1024; i += 256)
    attS[(i >> 8) * SX + (i & 255)] = att[i];
  for (int i = tid; i < 3072; i += 256) {
    int s = i >> 8, c4 = (i & 255) * 4;
    int h = c4 >> 8, cc = c4 & 255;
    *(ushort4*)&xl[(h * 12 + s) * SX + cc] =
        *(const ushort4*)(projS + (size_t)(base + s) * 3072 + c4);
  }
  __syncthreads();

  for (int t = tid; t < 288; t += 256) {
    const int e = t >> 2, h = t & 3;
    const unsigned short* pl = &xl[(h * 12 + se8[e]) * SX];
    const unsigned short* pr = projD + (size_t)(base + de8[e]) * 3072 + h * 256;
    const f32x4* pa = (const f32x4*)&attS[h * SX];
    float sum = 0.f;
    for (int q = 0; q < 64; ++q) {
      ushort4 a4 = *(const ushort4*)(pl + q * 4);
      ushort4 b4 = *(const ushort4*)(pr + q * 4);
      f32x4 av = pa[q];
      float v0 = b2f(a4.x) + b2f(b4.x); v0 = fmaxf(v0, 0.2f * v0);
      float v1 = b2f(a4.y) + b2f(b4.y); v1 = fmaxf(v1, 0.2f * v1);
      float v2 = b2f(a4.z) + b2f(b4.z); v2 = fmaxf(v2, 0.2f * v2);
      float v3 = b2f(a4.w) + b2f(b4.w); v3 = fmaxf(v3, 0.2f * v3);
      sum = fmaf(v0, av.x, sum); sum = fmaf(v1, av.y, sum);
      sum = fmaf(v2, av.z, sum); sum = fmaf(v3, av.w, sum);
    }
    sum *= LOG2E;
    alphaS[t] = sum;
    atomicMax(&mU[de8[e] * 4 + h], fenc(sum));
  }
  __syncthreads();

  for (int t = tid; t < 288; t += 256) {
    const int e = t >> 2, h = t & 3;
    const float m = fdec(mU[de8[e] * 4 + h]);
    const float wv = __builtin_amdgcn_exp2f(alphaS[t] - m);
    wS[t] = wv;
    atomicAdd(&denS[de8[e] * 4 + h], wv);
  }
  __syncthreads();

  for (int t = tid; t < 288; t += 256) {
    const int e = t >> 2, h = t & 3;
    const float inv = 0.25f * __builtin_amdgcn_rcpf(denS[de8[e] * 4 + h] + 1e-16f);
    atomicAdd(&A2f[de8[e] * 48 + h * 12 + se8[e]], wS[t] * inv);
  }
  __syncthreads();

  {
    const int c = tid;
    float xlv[48];
#pragma unroll
    for (int j = 0; j < 48; ++j) xlv[j] = b2f(xl[j * SX + c]);
    const float gb = gbias[c];
#pragma unroll
    for (int d = 0; d < 12; ++d) {
      const f32x4* arow = (const f32x4*)&A2f[d * 48];
      float s = 0.f;
#pragma unroll
      for (int jj = 0; jj < 12; ++jj) {
        f32x4 a4 = arow[jj];
        s = fmaf(a4.x, xlv[jj * 4 + 0], s);
        s = fmaf(a4.y, xlv[jj * 4 + 1], s);
        s = fmaf(a4.z, xlv[jj * 4 + 2], s);
        s = fmaf(a4.w, xlv[jj * 4 + 3], s);
      }
      outp[(size_t)(base + d) * 256 + c] = s + gb;
    }
  }
}

// ---------------------------------------------------------------------------
// CGConv edge stage (unchanged).
// ---------------------------------------------------------------------------
__global__ __launch_bounds__(256) void cg_edge(
    const unsigned short* __restrict__ pdF, const unsigned short* __restrict__ pdS,
    const unsigned short* __restrict__ psF, const unsigned short* __restrict__ psS,
    const unsigned short* __restrict__ hres,
    const float* __restrict__ gatp,
    const int* __restrict__ edges,
    unsigned short* __restrict__ outp)
{
  __shared__ __align__(8) unsigned short df[3072], dsb[3072];
  __shared__ __align__(8) unsigned short sfb[3072], ssb[3072];
  __shared__ unsigned char srcl[12 * 80];
  __shared__ int cnt[12];
  __shared__ int se_[72], de_[72];
  const int g = blockIdx.x, tid = threadIdx.x;
  const int base = g * 12;
  if (tid < 72) {
    se_[tid] = edges[g * 72 + tid] - base;
    de_[tid] = edges[ETOT + g * 72 + tid] - base;
  }
  for (int i = tid; i < 768; i += 256) {
    int s = i >> 6, c4 = (i & 63) * 4;
    size_t gb = (size_t)(base + s) * 3072 + c4;
    *(ushort4*)&df[s * 256 + c4]  = *(const ushort4*)(pdF + gb);
    *(ushort4*)&dsb[s * 256 + c4] = *(const ushort4*)(pdS + gb);
    *(ushort4*)&sfb[s * 256 + c4] = *(const ushort4*)(psF + gb);
    *(ushort4*)&ssb[s * 256 + c4] = *(const ushort4*)(psS + gb);
  }
  __syncthreads();
  if (tid < 12) {
    int n = 0;
    for (int e = 0; e < 72; ++e)
      if (de_[e] == tid) srcl[tid * 80 + (n++)] = (unsigned char)se_[e];
    cnt[tid] = n;
  }
  __syncthreads();
  const int c = tid;
  for (int d = 0; d < 12; ++d) {
    const float fd = b2f(df[d * 256 + c]);
    const float sd = b2f(dsb[d * 256 + c]);
    const int n = cnt[d];
    float acc = 0.f;
    for (int j = 0; j < n; ++j) {
      const int s = srcl[d * 80 + j];
      const float zf = fd + b2f(sfb[s * 256 + c]);
      const float zs = sd + b2f(ssb[s * 256 + c]);
      const float gate = __builtin_amdgcn_rcpf(1.f + __builtin_amdgcn_exp2f(-LOG2E * zf));
      const float e2 = __builtin_amdgcn_exp2f(-LOG2E * fabsf(zs));
      const float sp = fmaxf(zs, 0.f) + LN2 * __builtin_amdgcn_logf(1.f + e2);
      acc = fmaf(gate, sp, acc);
    }
    const size_t o = (size_t)(base + d) * 256 + c;
    outp[o] = f2b(b2f(hres[o]) + gatp[o] + acc);
  }
}

// ---------------------------------------------------------------------------
// logits: one wave per node, dot(f[128], W2) + b2
// ---------------------------------------------------------------------------
__global__ __launch_bounds__(256) void logits_kernel(
    const unsigned short* __restrict__ f, const float* __restrict__ W2,
    const float* __restrict__ b2, float* __restrict__ out)
{
  const int node = blockIdx.x * 4 + (threadIdx.x >> 6);
  const int lane = threadIdx.x & 63;
  const size_t o = (size_t)node * 128 + lane * 2;
  float s = b2f(f[o]) * W2[lane * 2] + b2f(f[o + 1]) * W2[lane * 2 + 1];
  for (int d = 32; d > 0; d >>= 1) s += __shfl_down(s, d, 64);
  if (lane == 0) out[node] = s + b2[0];
}

// ---------------------------------------------------------------------------
extern "C" void kernel_launch(void* const* d_in, const int* in_sizes, int n_in,
                              void* d_out, int out_size, void* d_ws, size_t ws_size,
                              hipStream_t stream) {
  const float* x_my    = (const float*)d_in[0];
  const float* x_opp   = (const float*)d_in[1];
  const int*   e_beats = (const int*)d_in[2];
  const int*   e_loses = (const int*)d_in[3];
  const int*   e_rb    = (const int*)d_in[4];
  const int*   e_rl    = (const int*)d_in[5];
  const float* enc_W   = (const float*)d_in[7];
  const float* enc_b   = (const float*)d_in[8];
  const float* gat_Wl  = (const float*)d_in[9];
  const float* gat_bl  = (const float*)d_in[10];
  const float* gat_Wr  = (const float*)d_in[11];
  const float* gat_br  = (const float*)d_in[12];
  const float* gat_att = (const float*)d_in[13];
  const float* gat_bsp = (const float*)d_in[14];
  const float* cg_Wf   = (const float*)d_in[15];
  const float* cg_bf   = (const float*)d_in[16];
  const float* cg_Ws   = (const float*)d_in[17];
  const float* cg_bs   = (const float*)d_in[18];
  const float* node_W  = (const float*)d_in[19];
  const float* node_b  = (const float*)d_in[20];
  const float* fin_W1  = (const float*)d_in[21];
  const float* fin_b1  = (const float*)d_in[22];
  const float* fin_W2  = (const float*)d_in[23];
  const float* fin_b2  = (const float*)d_in[24];

  char* wsp = (char*)d_ws;
  size_t off = 0;
  auto alloc = [&](size_t b) { char* p = wsp + off; off += (b + 255) & ~(size_t)255; return p; };
  unsigned short* wt_my   = (unsigned short*)alloc((size_t)2359296 * 2);
  unsigned short* wt_opp  = (unsigned short*)alloc((size_t)2359296 * 2);
  unsigned short* node_wt = (unsigned short*)alloc((size_t)196608 * 2);
  unsigned short* enc_wt  = (unsigned short*)alloc((size_t)8192 * 2);
  unsigned short* fin_w1t = (unsigned short*)alloc((size_t)32768 * 2);
  float*          bias_my = (float*)alloc((size_t)9216 * 4);
  float*          bias_op = (float*)alloc((size_t)9216 * 4);
  unsigned short* xb      = (unsigned short*)alloc((size_t)786432 * 2);
  unsigned short* Hb      = (unsigned short*)alloc((size_t)2 * NNODES * 256 * 2);
  unsigned short* proj_my = (unsigned short*)alloc((size_t)NNODES * 3072 * 2);
  unsigned short* proj_op = (unsigned short*)alloc((size_t)NNODES * 3072 * 2);
  float*          gat_my  = (float*)alloc((size_t)NNODES * 256 * 4);
  float*          gat_op  = (float*)alloc((size_t)NNODES * 256 * 4);
  unsigned short* node_in = (unsigned short*)alloc((size_t)2 * NNODES * 256 * 2);
  unsigned short* fbuf    = (unsigned short*)alloc((size_t)NNODES * 128 * 2);

  const int PACK_TOTAL = 2 * 2359296 + 196608 + 8192 + 32768 + 2 * 9216 + 2 * 393216;
  pack_kernel<<<(PACK_TOTAL + 255) / 256, 256, 0, stream>>>(
      gat_Wl, gat_Wr, cg_Wf, cg_Ws, node_W, enc_W, fin_W1,
      gat_bl, gat_br, cg_bf, cg_bs, x_my, x_opp,
      wt_my, wt_opp, node_wt, enc_wt, fin_w1t, bias_my, bias_op, xb);

  unsigned short* Hmy   = Hb;
  unsigned short* Hopp  = Hb + (size_t)NNODES * 256;
  unsigned short* ni_my = node_in;
  unsigned short* ni_op = node_in + (size_t)NNODES * 256;

  gemm64<<<dim3(384, 2), 256, 0, stream>>>(
      xb, xb, 32, enc_wt, enc_wt, enc_b, enc_b, Hb, Hb, 256, 32, 0, 384);

  for (int l = 0; l < 3; ++l) {
    gemm64<<<dim3(384, 24), 256, 0, stream>>>(
        Hmy, Hopp, 256,
        wt_my + (size_t)l * 786432, wt_opp + (size_t)l * 786432,
        bias_my + l * 3072, bias_op + l * 3072,
        proj_my, proj_op, 3072, 256, 0, 192);
    gat_edge<<<NGR, 256, 0, stream>>>(proj_my, proj_op, e_beats,
                                      gat_att + (l * 2 + 0) * 1024,
                                      gat_bsp + (l * 2 + 0) * 256, gat_op);
    gat_edge<<<NGR, 256, 0, stream>>>(proj_op + 1024, proj_my + 1024, e_rl,
                                      gat_att + (l * 2 + 1) * 1024,
                                      gat_bsp + (l * 2 + 1) * 256, gat_my);
    cg_edge<<<NGR, 256, 0, stream>>>(proj_op + 2048, proj_op + 2304,
                                     proj_my + 2048, proj_my + 2304,
                                     Hopp, gat_op, e_loses, ni_op);
    cg_edge<<<NGR, 256, 0, stream>>>(proj_my + 2560, proj_my + 2816,
                                     proj_op + 2560, proj_op + 2816,
                                     Hmy, gat_my, e_rb, ni_my);
    gemm64<<<dim3(384, 2), 256, 0, stream>>>(
        node_in, node_in, 256, node_wt + (size_t)l * 65536, node_wt + (size_t)l * 65536,
        node_b + l * 256, node_b + l * 256, Hb, Hb, 256, 256, 0, 384);
  }

  gemm64<<<dim3(192, 1), 256, 0, stream>>>(
      Hmy, Hmy, 256, fin_w1t, fin_w1t, fin_b1, fin_b1, fbuf, fbuf, 128, 256, 1, 192);
  logits_kernel<<<NNODES / 4, 256, 0, stream>>>(fbuf, fin_W2, fin_b2, (float*)d_out);
}